// Round 21
// baseline (1449.132 us; speedup 1.0000x reference)
//
#include <hip/hip_runtime.h>
#include <math.h>

#define BB 2
#define SS 2048
#define EE 512
#define HH 8
#define HD 64
#define LL 4
#define VV 50257
#define NTOK (BB*SS)
#define VPAD2 50432   // 197 * 256

typedef __bf16 bf16_t;
typedef bf16_t bf16x8 __attribute__((ext_vector_type(8)));
typedef float  f32x4  __attribute__((ext_vector_type(4)));

__device__ __forceinline__ void gload_lds16(const void* g, void* l) {
  __builtin_amdgcn_global_load_lds(
      (const __attribute__((address_space(1))) void*)g,
      (__attribute__((address_space(3))) void*)l, 16, 0, 0);
}

// ---------------- fused embedding + PE + LN1(layer0): x fp32, xn bf16 --------
__global__ __launch_bounds__(256) void embed_ln_kernel(
    const int* __restrict__ ids, const float* __restrict__ emb,
    const float* __restrict__ g, const float* __restrict__ b,
    float* __restrict__ x, bf16_t* __restrict__ xn) {
  int wv = threadIdx.x >> 6, lane = threadIdx.x & 63;
  int row = blockIdx.x * 4 + wv;
  int s = row & (SS - 1);
  int id = ids[row];
  const float* er = emb + (size_t)id * EE;
  float v[8];
  float sum = 0.f;
#pragma unroll
  for (int j = 0; j < 8; j++) {
    int e = lane * 8 + j;
    float freq = __expf((float)(e & ~1) * -0.01798894604f);
    float ang  = (float)s * freq;
    float pe   = (e & 1) ? __cosf(ang) : __sinf(ang);
    v[j] = er[e] + pe;
    sum += v[j];
  }
  float4* xp = reinterpret_cast<float4*>(x + (size_t)row * EE + lane * 8);
  xp[0] = make_float4(v[0], v[1], v[2], v[3]);
  xp[1] = make_float4(v[4], v[5], v[6], v[7]);
#pragma unroll
  for (int o = 32; o > 0; o >>= 1) sum += __shfl_xor(sum, o);
  float mean = sum * (1.f / EE);
  float var = 0.f;
#pragma unroll
  for (int j = 0; j < 8; j++) { float d = v[j] - mean; var += d * d; }
#pragma unroll
  for (int o = 32; o > 0; o >>= 1) var += __shfl_xor(var, o);
  float inv = rsqrtf(var * (1.f / EE) + 1e-5f);
  bf16_t tmp[8];
#pragma unroll
  for (int j = 0; j < 8; j++) {
    int e = lane * 8 + j;
    tmp[j] = (bf16_t)((v[j] - mean) * inv * g[e] + b[e]);
  }
  *reinterpret_cast<bf16x8*>(xn + (size_t)row * EE + lane * 8) = *reinterpret_cast<bf16x8*>(tmp);
}

// ---------------- merged weight transpose+convert (all 5 weight groups) ------
__device__ __forceinline__ void transpose_tile(const float* __restrict__ ip,
                                               bf16_t* __restrict__ op,
                                               int k0, int n0, int ldin, int ldout,
                                               int Nvalid, float* T) {
  int t = threadIdx.x;
  int r = t >> 2, cb = (t & 3) * 16;
#pragma unroll
  for (int i = 0; i < 16; i++) {
    int n = n0 + cb + i;
    T[r * 65 + cb + i] = (n < Nvalid) ? ip[(size_t)(k0 + r) * ldin + n] : 0.f;
  }
  __syncthreads();
  bf16_t tmp[16];
#pragma unroll
  for (int i = 0; i < 16; i++) tmp[i] = (bf16_t)T[(cb + i) * 65 + r];
  bf16_t* o = op + (size_t)(n0 + r) * ldout + k0 + cb;
  *reinterpret_cast<bf16x8*>(o)     = *reinterpret_cast<bf16x8*>(&tmp[0]);
  *reinterpret_cast<bf16x8*>(o + 8) = *reinterpret_cast<bf16x8*>(&tmp[8]);
}

__global__ __launch_bounds__(256) void wconv_all(
    const float* __restrict__ Wq, const float* __restrict__ Wk,
    const float* __restrict__ Wv, const float* __restrict__ Wo,
    const float* __restrict__ fw1, const float* __restrict__ fw2,
    const float* __restrict__ Wout,
    bf16_t* Wqkv, bf16_t* WoT, bf16_t* W1T, bf16_t* W2T, bf16_t* WoutT) {
  __shared__ float T[64 * 65];
  int bid = blockIdx.x;
  if (bid < 768) {
    int kx = bid & 7, z = bid >> 3;
    int l = z / 24, rem = z % 24, sec = rem >> 3, h = rem & 7;
    const float* W = sec == 0 ? Wq : (sec == 1 ? Wk : Wv);
    const float* ip = W + (size_t)(l * 8 + h) * (EE * HD);
    bf16_t* op = Wqkv + (size_t)l * (1536 * 512) + (size_t)(sec * 512 + h * 64) * 512;
    transpose_tile(ip, op, kx * 64, 0, HD, EE, HD, T);
  } else if (bid < 1024) {
    int r = bid - 768;
    int kx = r & 7, ny = (r >> 3) & 7, l = r >> 6;
    transpose_tile(Wo + (size_t)l * 512 * 512, WoT + (size_t)l * 512 * 512,
                   kx * 64, ny * 64, 512, 512, 512, T);
  } else if (bid < 2048) {
    int r = bid - 1024;
    int kx = r & 7, ny = (r >> 3) & 31, l = r >> 8;
    transpose_tile(fw1 + (size_t)l * 512 * 2048, W1T + (size_t)l * 2048 * 512,
                   kx * 64, ny * 64, 2048, 512, 2048, T);
  } else if (bid < 3072) {
    int r = bid - 2048;
    int kx = r & 31, ny = (r >> 5) & 7, l = r >> 8;
    transpose_tile(fw2 + (size_t)l * 2048 * 512, W2T + (size_t)l * 512 * 2048,
                   kx * 64, ny * 64, 512, 2048, 512, T);
  } else {
    int r = bid - 3072;
    int kx = r & 7, ny = r >> 3;
    transpose_tile(Wout, WoutT, kx * 64, ny * 64, VV, 512, VV, T);
  }
}

// ---------------- gemm3_64: TM=64, 3-buffer depth-3 pipeline, 1 barrier/step --
// MODE: 0=QKV scatter, 1=bias+GELU->bf16.
template<int MODE>
__global__ __launch_bounds__(256) void gemm3_64(
    const bf16_t* __restrict__ A, const bf16_t* __restrict__ Bt,
    int M, int N, int K,
    const float* __restrict__ bias, bf16_t* __restrict__ Cb,
    bf16_t* __restrict__ qo, bf16_t* __restrict__ ko, bf16_t* __restrict__ vo) {
  constexpr int TM = 64, MI = 2;
  __shared__ __align__(16) bf16_t As[3][TM * 64];
  __shared__ __align__(16) bf16_t Bs[3][128 * 64];
  int tid = threadIdx.x, lane = tid & 63, w = tid >> 6;
  int lr = lane & 15, lg = lane >> 4;
  int m0 = blockIdx.y * TM, n0 = blockIdx.x * 128;
  f32x4 acc[MI][4];
#pragma unroll
  for (int i = 0; i < MI; i++)
#pragma unroll
    for (int j = 0; j < 4; j++) acc[i][j] = (f32x4){0.f, 0.f, 0.f, 0.f};
  int wr = w >> 1, wc = w & 1;

  const bf16_t* Abase = A  + (size_t)(m0 + lr) * K + lg * 8;
  const bf16_t* Bbase = Bt + (size_t)(n0 + lr) * K + lg * 8;

  auto stage = [&](int buf, int k0) {
#pragma unroll
    for (int i = 0; i < MI; i++) {
      int c = w * MI + i;
      gload_lds16(Abase + (size_t)(c >> 1) * 16 * K + k0 + (c & 1) * 32,
                  (char*)&As[buf][0] + c * 1024);
    }
#pragma unroll
    for (int i = 0; i < 4; i++) {
      int c = w * 4 + i;
      gload_lds16(Bbase + (size_t)(c >> 1) * 16 * K + k0 + (c & 1) * 32,
                  (char*)&Bs[buf][0] + c * 1024);
    }
  };

  int nk = K >> 6;
  stage(0, 0);
  if (nk > 1) stage(1, 64);
  for (int k = 0; k < nk; k++) {
    int cur = k % 3;
    if (k + 1 < nk) asm volatile("s_waitcnt vmcnt(6)" ::: "memory");
    else            asm volatile("s_waitcnt vmcnt(0)" ::: "memory");
    __builtin_amdgcn_s_barrier();
    __builtin_amdgcn_s_setprio(1);
#pragma unroll
    for (int kk = 0; kk < 2; kk++) {
      bf16x8 afr[MI], bfr[4];
#pragma unroll
      for (int mi = 0; mi < MI; mi++)
        afr[mi] = *reinterpret_cast<const bf16x8*>(
            &As[cur][(((wr * MI + mi) << 1) + kk) * 512 + lane * 8]);
#pragma unroll
      for (int ni = 0; ni < 4; ni++)
        bfr[ni] = *reinterpret_cast<const bf16x8*>(
            &Bs[cur][(((wc * 4 + ni) << 1) + kk) * 512 + lane * 8]);
#pragma unroll
      for (int mi = 0; mi < MI; mi++)
#pragma unroll
        for (int ni = 0; ni < 4; ni++)
          acc[mi][ni] = __builtin_amdgcn_mfma_f32_16x16x32_bf16(afr[mi], bfr[ni], acc[mi][ni], 0, 0, 0);
    }
    __builtin_amdgcn_s_setprio(0);
    if (k + 2 < nk) stage((k + 2) % 3, (k + 2) << 6);
  }

#pragma unroll
  for (int mi = 0; mi < MI; mi++)
#pragma unroll
    for (int ni = 0; ni < 4; ni++) {
      int colg = n0 + wc * 64 + ni * 16 + lr;
#pragma unroll
      for (int j = 0; j < 4; j++) {
        int rowg = m0 + wr * (TM / 2) + mi * 16 + lg * 4 + j;
        float v = acc[mi][ni][j];
        if (MODE == 0) {
          int sec = colg >> 9, cc = colg & 511, hh = cc >> 6, dd = cc & 63;
          int bi = rowg >> 11, s = rowg & 2047;
          if (sec == 0)      qo[(((size_t)bi * HH + hh) * SS + s) * HD + dd] = (bf16_t)(v * 0.125f);
          else if (sec == 1) ko[(((size_t)bi * HH + hh) * SS + s) * HD + dd] = (bf16_t)v;
          else               vo[(((size_t)bi * HH + hh) * HD + dd) * SS + s] = (bf16_t)v;
        } else {
          v += bias[colg];
          v = 0.5f * v * (1.f + erff(v * 0.70710678f));
          Cb[(size_t)rowg * N + colg] = (bf16_t)v;
        }
      }
    }
}

// ---------------- gemm_ln: row-complete GEMM + residual + fused LayerNorm ----
// C[16 x 512] per block (TM=16, TN=512 = full row). 512 threads, 8 waves, each
// wave owns 64 cols (NI=4). Epilogue: v = acc (+bias) + x_old; cross-wave LDS
// reduction of (sum, sumsq) per row -> mean/var -> writes x (fp32 residual)
// and xn = LN(v) (bf16). Removes the standalone ln_kernel dispatch + x re-read.
template<bool HASBIAS>
__global__ __launch_bounds__(512) void gemm_ln(
    const bf16_t* __restrict__ A, const bf16_t* __restrict__ Bt, int K,
    const float* __restrict__ bias, float* x,
    const float* __restrict__ g, const float* __restrict__ b,
    bf16_t* __restrict__ xn) {
  __shared__ __align__(16) bf16_t As[2 * 512];     // 2 KB  (16 rows x 64 k)
  __shared__ __align__(16) bf16_t Bs[64 * 512];    // 64 KB (512 cols x 64 k)
  __shared__ float pSum[128], pSqr[128];           // 8 waves x 16 rows
  int tid = threadIdx.x, lane = tid & 63, w = tid >> 6;
  int lr = lane & 15, lg = lane >> 4;
  int m0 = blockIdx.x * 16;

  f32x4 acc[4];
#pragma unroll
  for (int i = 0; i < 4; i++) acc[i] = (f32x4){0.f, 0.f, 0.f, 0.f};

  const bf16_t* Abase = A  + (size_t)(m0 + lr) * K + lg * 8;
  const bf16_t* Bbase = Bt + (size_t)lr * K + lg * 8;

  int nk = K >> 6;
  for (int k = 0; k < nk; k++) {
    int k0 = k << 6;
    // B: 64 sub-blocks (col-group rg=cb>>1 of 16 cols, k-half cb&1), 8/wave
#pragma unroll
    for (int i = 0; i < 8; i++) {
      int cb = w * 8 + i;
      gload_lds16(Bbase + (size_t)(cb >> 1) * 16 * K + k0 + (cb & 1) * 32,
                  (char*)Bs + cb * 1024);
    }
    // A: 2 sub-blocks, waves 0/1
    if (w < 2)
      gload_lds16(Abase + k0 + w * 32, (char*)As + w * 1024);
    __syncthreads();
    __builtin_amdgcn_s_setprio(1);
#pragma unroll
    for (int kk = 0; kk < 2; kk++) {
      bf16x8 afr = *reinterpret_cast<const bf16x8*>(&As[kk * 512 + lane * 8]);
      bf16x8 bfr[4];
#pragma unroll
      for (int ni = 0; ni < 4; ni++)
        bfr[ni] = *reinterpret_cast<const bf16x8*>(
            &Bs[(((w * 4 + ni) << 1) + kk) * 512 + lane * 8]);
#pragma unroll
      for (int ni = 0; ni < 4; ni++)
        acc[ni] = __builtin_amdgcn_mfma_f32_16x16x32_bf16(afr, bfr[ni], acc[ni], 0, 0, 0);
    }
    __builtin_amdgcn_s_setprio(0);
    __syncthreads();
  }

  // epilogue: v = acc (+bias) + x_old
  float v[4][4];
  float bi4[4];
#pragma unroll
  for (int ni = 0; ni < 4; ni++) {
    int colg = w * 64 + ni * 16 + lr;
    bi4[ni] = HASBIAS ? bias[colg] : 0.f;
#pragma unroll
    for (int j = 0; j < 4; j++) {
      int rowg = m0 + lg * 4 + j;
      v[ni][j] = acc[ni][j] + bi4[ni] + x[(size_t)rowg * EE + colg];
    }
  }
  // per-lane partial (sum, sumsq) over this wave's 64 cols, per row j
  float s1[4], s2[4];
#pragma unroll
  for (int j = 0; j < 4; j++) { s1[j] = 0.f; s2[j] = 0.f; }
#pragma unroll
  for (int ni = 0; ni < 4; ni++)
#pragma unroll
    for (int j = 0; j < 4; j++) { s1[j] += v[ni][j]; s2[j] += v[ni][j] * v[ni][j]; }
#pragma unroll
  for (int msk = 1; msk <= 8; msk <<= 1)
#pragma unroll
    for (int j = 0; j < 4; j++) {
      s1[j] += __shfl_xor(s1[j], msk);
      s2[j] += __shfl_xor(s2[j], msk);
    }
  if (lr == 0) {
#pragma unroll
    for (int j = 0; j < 4; j++) {
      pSum[w * 16 + lg * 4 + j] = s1[j];
      pSqr[w * 16 + lg * 4 + j] = s2[j];
    }
  }
  __syncthreads();
  float mean[4], inv[4];
#pragma unroll
  for (int j = 0; j < 4; j++) {
    int row = lg * 4 + j;
    float t1 = 0.f, t2 = 0.f;
#pragma unroll
    for (int w2 = 0; w2 < 8; w2++) { t1 += pSum[w2 * 16 + row]; t2 += pSqr[w2 * 16 + row]; }
    mean[j] = t1 * (1.f / EE);
    float var = t2 * (1.f / EE) - mean[j] * mean[j];
    inv[j] = rsqrtf(var + 1e-5f);
  }
#pragma unroll
  for (int ni = 0; ni < 4; ni++) {
    int colg = w * 64 + ni * 16 + lr;
    float gg = g[colg], bb = b[colg];
#pragma unroll
    for (int j = 0; j < 4; j++) {
      int rowg = m0 + lg * 4 + j;
      x[(size_t)rowg * EE + colg] = v[ni][j];
      xn[(size_t)rowg * EE + colg] = (bf16_t)((v[ni][j] - mean[j]) * inv[j] * gg + bb);
    }
  }
}

// ---------------- vocab GEMM: 256², single-buffer, N-fastest, NT epilogue ----
__global__ __launch_bounds__(512) void gemm256_out(
    const bf16_t* __restrict__ A, const bf16_t* __restrict__ Bt,
    const float* __restrict__ bias, float* __restrict__ C) {
  __shared__ __align__(16) char smem[64 * 260 * 4];
  bf16_t* As = (bf16_t*)smem;
  bf16_t* Bs = (bf16_t*)(smem + 32768);
  float*  Ep = (float*)smem;
  int tid = threadIdx.x, lane = tid & 63, w = tid >> 6;
  int lr = lane & 15, lg = lane >> 4;
  int bid = blockIdx.x;
  int n0 = (bid % 197) * 256, m0 = (bid / 197) * 256;   // N-fastest
  int wr = w >> 2, wc = w & 3;
  f32x4 acc[8][4];
#pragma unroll
  for (int i = 0; i < 8; i++)
#pragma unroll
    for (int j = 0; j < 4; j++) acc[i][j] = (f32x4){0.f, 0.f, 0.f, 0.f};

  const bf16_t* Abase = A  + (size_t)(m0 + lr) * 512 + lg * 8;
  const bf16_t* Bbase = Bt + (size_t)(n0 + lr) * 512 + lg * 8;

  for (int k0 = 0; k0 < 512; k0 += 64) {
#pragma unroll
    for (int i = 0; i < 4; i++) {
      int c = w * 4 + i;
      gload_lds16(Abase + (size_t)(c >> 1) * 16 * 512 + k0 + (c & 1) * 32,
                  (char*)As + c * 1024);
      gload_lds16(Bbase + (size_t)(c >> 1) * 16 * 512 + k0 + (c & 1) * 32,
                  (char*)Bs + c * 1024);
    }
    __syncthreads();
#pragma unroll
    for (int kk = 0; kk < 2; kk++) {
      bf16x8 afr[8], bfr[4];
#pragma unroll
      for (int mi = 0; mi < 8; mi++)
        afr[mi] = *reinterpret_cast<const bf16x8*>(
            &As[(((wr * 8 + mi) << 1) + kk) * 512 + lane * 8]);
#pragma unroll
      for (int ni = 0; ni < 4; ni++)
        bfr[ni] = *reinterpret_cast<const bf16x8*>(
            &Bs[(((wc * 4 + ni) << 1) + kk) * 512 + lane * 8]);
#pragma unroll
      for (int mi = 0; mi < 8; mi++)
#pragma unroll
        for (int ni = 0; ni < 4; ni++)
          acc[mi][ni] = __builtin_amdgcn_mfma_f32_16x16x32_bf16(afr[mi], bfr[ni], acc[mi][ni], 0, 0, 0);
    }
    __syncthreads();
  }

  int colBase = n0 + (tid & 63) * 4;
  float b0 = 0.f, b1 = 0.f, b2 = 0.f, b3 = 0.f;
  if (colBase + 3 < VV) {
    float4 bv = *reinterpret_cast<const float4*>(bias + colBase);
    b0 = bv.x; b1 = bv.y; b2 = bv.z; b3 = bv.w;
  } else {
    if (colBase     < VV) b0 = bias[colBase];
    if (colBase + 1 < VV) b1 = bias[colBase + 1];
    if (colBase + 2 < VV) b2 = bias[colBase + 2];
  }
  int rw = tid >> 6;
  for (int ch = 0; ch < 4; ch++) {
    __syncthreads();
    if (wr == (ch >> 1)) {
      int mib = (ch & 1) * 4;
#pragma unroll
      for (int mi2 = 0; mi2 < 4; mi2++)
#pragma unroll
        for (int ni = 0; ni < 4; ni++) {
          int col = wc * 64 + ni * 16 + lr;
#pragma unroll
          for (int j = 0; j < 4; j++)
            Ep[(mi2 * 16 + lg * 4 + j) * 260 + col] = acc[mib + mi2][ni][j];
        }
    }
    __syncthreads();
#pragma unroll
    for (int pass = 0; pass < 8; pass++) {
      int r = pass * 8 + rw;
      f32x4 v = *reinterpret_cast<const f32x4*>(&Ep[r * 260 + (tid & 63) * 4]);
      v[0] += b0; v[1] += b1; v[2] += b2; v[3] += b3;
      float* dst = &C[(size_t)(m0 + ch * 64 + r) * VV + colBase];
      if (colBase + 3 < VV) {
        __builtin_nontemporal_store(v, reinterpret_cast<f32x4*>(dst));
      } else {
        if (colBase     < VV) __builtin_nontemporal_store(v[0], dst);
        if (colBase + 1 < VV) __builtin_nontemporal_store(v[1], dst + 1);
        if (colBase + 2 < VV) __builtin_nontemporal_store(v[2], dst + 2);
      }
    }
  }
}

// ---------------- flash attention v5: QBLK=64, 3-buffer depth-3 K/V pipeline --
#define QBLK 64
#define KVB 64
__global__ __launch_bounds__(256) void attn_kernel(
    const bf16_t* __restrict__ qb, const bf16_t* __restrict__ kb,
    const bf16_t* __restrict__ vT, const int* __restrict__ amask,
    bf16_t* __restrict__ ab) {
  __shared__ bf16_t Qs[QBLK][72];
  __shared__ bf16_t Ps[QBLK][72];
  __shared__ __align__(16) bf16_t Ks[3][KVB * 64];
  __shared__ __align__(16) bf16_t Vs[3][KVB * 64];
  __shared__ float kmAll[SS];
  int tid = threadIdx.x, lane = tid & 63, w = tid >> 6;
  int lr = lane & 15, lg = lane >> 4;
  int bid = blockIdx.x;
  int bh = bid & 15;
  int qi = bid >> 4;
  int qq = (qi < 16) ? qi : 47 - qi;
  int q0 = qq * QBLK;
  int b = bh >> 3, h = bh & 7;
  const bf16_t* Qg = qb + (size_t)bh * SS * HD;
  const bf16_t* Kg = kb + (size_t)bh * SS * HD;
  const bf16_t* Vg = vT + (size_t)bh * HD * SS;

  {
    int r = tid >> 2, c = (tid & 3) * 16;
    const uint4* s = reinterpret_cast<const uint4*>(Qg + (size_t)(q0 + r) * HD + c);
    uint4 a0 = s[0], a1 = s[1];
    *reinterpret_cast<uint4*>(&Qs[r][c])     = a0;
    *reinterpret_cast<uint4*>(&Qs[r][c + 8]) = a1;
  }
#pragma unroll
  for (int i = 0; i < 8; i++) {
    int s = i * 256 + tid;
    kmAll[s] = amask[b * SS + s] ? 0.f : -1e30f;
  }

  auto stageKV = [&](int buf, int kv0) {
#pragma unroll
    for (int i = 0; i < 4; i++) {
      int c = w * 4 + i;
      if (c < 8) {
        gload_lds16(Kg + (size_t)(kv0 + (c >> 1) * 16 + lr) * HD + (c & 1) * 32 + lg * 8,
                    (char*)&Ks[buf][0] + c * 1024);
      } else {
        int cc = c - 8;
        gload_lds16(Vg + (size_t)((cc >> 1) * 16 + lr) * SS + kv0 + (cc & 1) * 32 + lg * 8,
                    (char*)&Vs[buf][0] + cc * 1024);
      }
    }
  };

  f32x4 o[4];
  f32x4 m_run, l_run;
  m_run = (f32x4){-1e30f, -1e30f, -1e30f, -1e30f};
  l_run = (f32x4){0.f, 0.f, 0.f, 0.f};
#pragma unroll
  for (int nd = 0; nd < 4; nd++) o[nd] = (f32x4){0.f, 0.f, 0.f, 0.f};

  int ntile = qq + 1;
  stageKV(0, 0);
  if (ntile > 1) stageKV(1, KVB);
  __syncthreads();

  for (int t = 0; t < ntile; t++) {
    int buf = t % 3;
    int kv0 = t * KVB;
    if (t + 1 < ntile) asm volatile("s_waitcnt vmcnt(4)" ::: "memory");
    else               asm volatile("s_waitcnt vmcnt(0)" ::: "memory");
    __builtin_amdgcn_s_barrier();

    f32x4 sc[4];
#pragma unroll
    for (int ni = 0; ni < 4; ni++) sc[ni] = (f32x4){0.f, 0.f, 0.f, 0.f};
#pragma unroll
    for (int kk = 0; kk < 2; kk++) {
      bf16x8 af = *reinterpret_cast<const bf16x8*>(&Qs[w * 16 + lr][kk * 32 + lg * 8]);
      bf16x8 bf[4];
#pragma unroll
      for (int ni = 0; ni < 4; ni++)
        bf[ni] = *reinterpret_cast<const bf16x8*>(&Ks[buf][((ni << 1) + kk) * 512 + lane * 8]);
#pragma unroll
      for (int ni = 0; ni < 4; ni++)
        sc[ni] = __builtin_amdgcn_mfma_f32_16x16x32_bf16(af, bf[ni], sc[ni], 0, 0, 0);
    }

    {
      int qrb = q0 + w * 16 + lg * 4;
      float kmv[4];
#pragma unroll
      for (int ni = 0; ni < 4; ni++) kmv[ni] = kmAll[kv0 + ni * 16 + lr];
#pragma unroll
      for (int ni = 0; ni < 4; ni++) {
        int kg = kv0 + ni * 16 + lr;
#pragma unroll
        for (int j = 0; j < 4; j++) {
          float s = sc[ni][j] + kmv[ni];
          sc[ni][j] = (kg <= qrb + j) ? s : -1e30f;
        }
      }
      f32x4 rmax = sc[0];
#pragma unroll
      for (int ni = 1; ni < 4; ni++)
#pragma unroll
        for (int j = 0; j < 4; j++) rmax[j] = fmaxf(rmax[j], sc[ni][j]);
#pragma unroll
      for (int msk = 1; msk <= 8; msk <<= 1)
#pragma unroll
        for (int j = 0; j < 4; j++) rmax[j] = fmaxf(rmax[j], __shfl_xor(rmax[j], msk));
      f32x4 mnew, corr;
#pragma unroll
      for (int j = 0; j < 4; j++) {
        mnew[j] = fmaxf(m_run[j], rmax[j]);
        corr[j] = __expf(m_run[j] - mnew[j]);
      }
      m_run = mnew;
      f32x4 rs = (f32x4){0.f, 0.f, 0.f, 0.f};
#pragma unroll
      for (int ni = 0; ni < 4; ni++) {
#pragma unroll
        for (int j = 0; j < 4; j++) {
          float p = __expf(sc[ni][j] - mnew[j]);
          rs[j] += p;
          Ps[w * 16 + lg * 4 + j][ni * 16 + lr] = (bf16_t)p;
        }
      }
#pragma unroll
      for (int msk = 1; msk <= 8; msk <<= 1)
#pragma unroll
        for (int j = 0; j < 4; j++) rs[j] += __shfl_xor(rs[j], msk);
#pragma unroll
      for (int j = 0; j < 4; j++) l_run[j] = l_run[j] * corr[j] + rs[j];
#pragma unroll
      for (int nd = 0; nd < 4; nd++) o[nd] = o[nd] * corr;
    }

#pragma unroll
    for (int kc = 0; kc < 2; kc++) {
      bf16x8 pa = *reinterpret_cast<const bf16x8*>(&Ps[w * 16 + lr][kc * 32 + lg * 8]);
      bf16x8 vb[4];
#pragma unroll
      for (int nd = 0; nd < 4; nd++)
        vb[nd] = *reinterpret_cast<const bf16x8*>(&Vs[buf][((nd << 1) + kc) * 512 + lane * 8]);
#pragma unroll
      for (int nd = 0; nd < 4; nd++)
        o[nd] = __builtin_amdgcn_mfma_f32_16x16x32_bf16(pa, vb[nd], o[nd], 0, 0, 0);
    }

    if (t + 2 < ntile) stageKV((t + 2) % 3, kv0 + 2 * KVB);
  }

  f32x4 linv;
#pragma unroll
  for (int j = 0; j < 4; j++) linv[j] = 1.f / l_run[j];
#pragma unroll
  for (int nd = 0; nd < 4; nd++)
#pragma unroll
    for (int j = 0; j < 4; j++) {
      int rowg = b * SS + q0 + w * 16 + lg * 4 + j;
      int col = h * HD + nd * 16 + lr;
      ab[(size_t)rowg * EE + col] = (bf16_t)(o[nd][j] * linv[j]);
    }
}

extern "C" void kernel_launch(void* const* d_in, const int* in_sizes, int n_in,
                              void* d_out, int out_size, void* d_ws, size_t ws_size,
                              hipStream_t stream) {
  const int*   ids   = (const int*)d_in[0];
  const int*   amask = (const int*)d_in[1];
  const float* emb   = (const float*)d_in[2];
  const float* Wq    = (const float*)d_in[3];
  const float* Wk    = (const float*)d_in[4];
  const float* Wv    = (const float*)d_in[5];
  const float* Wo    = (const float*)d_in[6];
  const float* ln1g  = (const float*)d_in[7];
  const float* ln1b  = (const float*)d_in[8];
  const float* ln2g  = (const float*)d_in[9];
  const float* ln2b  = (const float*)d_in[10];
  const float* fw1   = (const float*)d_in[11];
  const float* fb1   = (const float*)d_in[12];
  const float* fw2   = (const float*)d_in[13];
  const float* fb2   = (const float*)d_in[14];
  const float* lnfg  = (const float*)d_in[15];
  const float* lnfb  = (const float*)d_in[16];
  const float* Wout  = (const float*)d_in[17];
  const float* bout  = (const float*)d_in[18];
  float* out = (float*)d_out;

  float*  x     = (float*)d_ws;
  bf16_t* xn    = (bf16_t*)((char*)d_ws + (8u << 20));
  bf16_t* WoutT = (bf16_t*)((char*)d_ws + (12u << 20));
  char* sc = (char*)d_out;
  bf16_t* qbuf = (bf16_t*)(sc);
  bf16_t* kbuf = (bf16_t*)(sc + 4194304);
  bf16_t* vTb  = (bf16_t*)(sc + 8388608);
  bf16_t* ab   = (bf16_t*)(sc + 12582912);
  bf16_t* hb   = (bf16_t*)(sc + 16777216);
  bf16_t* Wqkv = (bf16_t*)(sc + 33554432);
  bf16_t* WoT  = (bf16_t*)(sc + 39845888);
  bf16_t* W1T  = (bf16_t*)(sc + 41943040);
  bf16_t* W2T  = (bf16_t*)(sc + 50331648);

  wconv_all<<<dim3(3072 + 8 * (VPAD2 / 64)), 256, 0, stream>>>(
      Wq, Wk, Wv, Wo, fw1, fw2, Wout, Wqkv, WoT, W1T, W2T, WoutT);

  embed_ln_kernel<<<NTOK / 4, 256, 0, stream>>>(ids, emb, ln1g, ln1b, x, xn);

  for (int l = 0; l < LL; l++) {
    gemm3_64<0><<<dim3(12, 64), 256, 0, stream>>>(xn, Wqkv + (size_t)l * 1536 * 512,
        NTOK, 1536, 512, nullptr, nullptr, qbuf, kbuf, vTb);
    attn_kernel<<<dim3(512), 256, 0, stream>>>(qbuf, kbuf, vTb, amask, ab);
    // Wo GEMM + residual + LN2 fused
    gemm_ln<false><<<dim3(NTOK / 16), 512, 0, stream>>>(
        ab, WoT + (size_t)l * 512 * 512, 512, nullptr, x,
        ln2g + l * EE, ln2b + l * EE, xn);
    gemm3_64<1><<<dim3(16, 64), 256, 0, stream>>>(xn, W1T + (size_t)l * 2048 * 512,
        NTOK, 2048, 512, fb1 + l * 2048, hb, nullptr, nullptr, nullptr);
    // FFN2 GEMM + residual + LN1(next layer) / LNf(last layer) fused
    const float* gg = (l == LL - 1) ? lnfg : ln1g + (l + 1) * EE;
    const float* bb = (l == LL - 1) ? lnfb : ln1b + (l + 1) * EE;
    gemm_ln<true><<<dim3(NTOK / 16), 512, 0, stream>>>(
        hb, W2T + (size_t)l * 512 * 2048, 2048, fb2 + l * EE, x, gg, bb, xn);
  }
  gemm256_out<<<dim3(16 * (VPAD2 / 256)), 512, 0, stream>>>(xn, WoutT, bout, out);
}

// Round 22
// 1277.850 us; speedup vs baseline: 1.1340x; 1.1340x over previous
//
#include <hip/hip_runtime.h>
#include <math.h>

#define BB 2
#define SS 2048
#define EE 512
#define HH 8
#define HD 64
#define LL 4
#define VV 50257
#define NTOK (BB*SS)
#define VPAD2 50432   // 197 * 256

typedef __bf16 bf16_t;
typedef bf16_t bf16x8 __attribute__((ext_vector_type(8)));
typedef float  f32x4  __attribute__((ext_vector_type(4)));

__device__ __forceinline__ void gload_lds16(const void* g, void* l) {
  __builtin_amdgcn_global_load_lds(
      (const __attribute__((address_space(1))) void*)g,
      (__attribute__((address_space(3))) void*)l, 16, 0, 0);
}

// ---------------- fused embedding + PE + LN1(layer0): x fp32, xn bf16 --------
__global__ __launch_bounds__(256) void embed_ln_kernel(
    const int* __restrict__ ids, const float* __restrict__ emb,
    const float* __restrict__ g, const float* __restrict__ b,
    float* __restrict__ x, bf16_t* __restrict__ xn) {
  int wv = threadIdx.x >> 6, lane = threadIdx.x & 63;
  int row = blockIdx.x * 4 + wv;
  int s = row & (SS - 1);
  int id = ids[row];
  const float* er = emb + (size_t)id * EE;
  float v[8];
  float sum = 0.f;
#pragma unroll
  for (int j = 0; j < 8; j++) {
    int e = lane * 8 + j;
    float freq = __expf((float)(e & ~1) * -0.01798894604f);
    float ang  = (float)s * freq;
    float pe   = (e & 1) ? __cosf(ang) : __sinf(ang);
    v[j] = er[e] + pe;
    sum += v[j];
  }
  float4* xp = reinterpret_cast<float4*>(x + (size_t)row * EE + lane * 8);
  xp[0] = make_float4(v[0], v[1], v[2], v[3]);
  xp[1] = make_float4(v[4], v[5], v[6], v[7]);
#pragma unroll
  for (int o = 32; o > 0; o >>= 1) sum += __shfl_xor(sum, o);
  float mean = sum * (1.f / EE);
  float var = 0.f;
#pragma unroll
  for (int j = 0; j < 8; j++) { float d = v[j] - mean; var += d * d; }
#pragma unroll
  for (int o = 32; o > 0; o >>= 1) var += __shfl_xor(var, o);
  float inv = rsqrtf(var * (1.f / EE) + 1e-5f);
  bf16_t tmp[8];
#pragma unroll
  for (int j = 0; j < 8; j++) {
    int e = lane * 8 + j;
    tmp[j] = (bf16_t)((v[j] - mean) * inv * g[e] + b[e]);
  }
  *reinterpret_cast<bf16x8*>(xn + (size_t)row * EE + lane * 8) = *reinterpret_cast<bf16x8*>(tmp);
}

// ---------------- LayerNorm: fp32 in -> bf16 out, one wave per row ----------------
__global__ __launch_bounds__(256) void ln_kernel(const float* __restrict__ in,
                                                 bf16_t* __restrict__ out,
                                                 const float* __restrict__ g,
                                                 const float* __restrict__ b) {
  int wv = threadIdx.x >> 6, lane = threadIdx.x & 63;
  int row = blockIdx.x * 4 + wv;
  const float4* r = reinterpret_cast<const float4*>(in + (size_t)row * EE) + lane * 2;
  float4 v0 = r[0], v1 = r[1];
  float s = v0.x + v0.y + v0.z + v0.w + v1.x + v1.y + v1.z + v1.w;
#pragma unroll
  for (int o = 32; o > 0; o >>= 1) s += __shfl_xor(s, o);
  float mean = s * (1.f / EE);
  float d0 = v0.x-mean, d1 = v0.y-mean, d2 = v0.z-mean, d3 = v0.w-mean;
  float d4 = v1.x-mean, d5 = v1.y-mean, d6 = v1.z-mean, d7 = v1.w-mean;
  float var = d0*d0+d1*d1+d2*d2+d3*d3+d4*d4+d5*d5+d6*d6+d7*d7;
#pragma unroll
  for (int o = 32; o > 0; o >>= 1) var += __shfl_xor(var, o);
  float inv = rsqrtf(var * (1.f / EE) + 1e-5f);
  const float4* gp = reinterpret_cast<const float4*>(g) + lane * 2;
  const float4* bp = reinterpret_cast<const float4*>(b) + lane * 2;
  float4 g0 = gp[0], g1 = gp[1], b0 = bp[0], b1 = bp[1];
  bf16_t tmp[8];
  tmp[0] = (bf16_t)(d0*inv*g0.x + b0.x); tmp[1] = (bf16_t)(d1*inv*g0.y + b0.y);
  tmp[2] = (bf16_t)(d2*inv*g0.z + b0.z); tmp[3] = (bf16_t)(d3*inv*g0.w + b0.w);
  tmp[4] = (bf16_t)(d4*inv*g1.x + b1.x); tmp[5] = (bf16_t)(d5*inv*g1.y + b1.y);
  tmp[6] = (bf16_t)(d6*inv*g1.z + b1.z); tmp[7] = (bf16_t)(d7*inv*g1.w + b1.w);
  *reinterpret_cast<bf16x8*>(out + (size_t)row * EE + lane * 8) = *reinterpret_cast<bf16x8*>(tmp);
}

// ---------------- merged weight transpose+convert (all 5 weight groups) ------
__device__ __forceinline__ void transpose_tile(const float* __restrict__ ip,
                                               bf16_t* __restrict__ op,
                                               int k0, int n0, int ldin, int ldout,
                                               int Nvalid, float* T) {
  int t = threadIdx.x;
  int r = t >> 2, cb = (t & 3) * 16;
#pragma unroll
  for (int i = 0; i < 16; i++) {
    int n = n0 + cb + i;
    T[r * 65 + cb + i] = (n < Nvalid) ? ip[(size_t)(k0 + r) * ldin + n] : 0.f;
  }
  __syncthreads();
  bf16_t tmp[16];
#pragma unroll
  for (int i = 0; i < 16; i++) tmp[i] = (bf16_t)T[(cb + i) * 65 + r];
  bf16_t* o = op + (size_t)(n0 + r) * ldout + k0 + cb;
  *reinterpret_cast<bf16x8*>(o)     = *reinterpret_cast<bf16x8*>(&tmp[0]);
  *reinterpret_cast<bf16x8*>(o + 8) = *reinterpret_cast<bf16x8*>(&tmp[8]);
}

__global__ __launch_bounds__(256) void wconv_all(
    const float* __restrict__ Wq, const float* __restrict__ Wk,
    const float* __restrict__ Wv, const float* __restrict__ Wo,
    const float* __restrict__ fw1, const float* __restrict__ fw2,
    const float* __restrict__ Wout,
    bf16_t* Wqkv, bf16_t* WoT, bf16_t* W1T, bf16_t* W2T, bf16_t* WoutT) {
  __shared__ float T[64 * 65];
  int bid = blockIdx.x;
  if (bid < 768) {
    int kx = bid & 7, z = bid >> 3;
    int l = z / 24, rem = z % 24, sec = rem >> 3, h = rem & 7;
    const float* W = sec == 0 ? Wq : (sec == 1 ? Wk : Wv);
    const float* ip = W + (size_t)(l * 8 + h) * (EE * HD);
    bf16_t* op = Wqkv + (size_t)l * (1536 * 512) + (size_t)(sec * 512 + h * 64) * 512;
    transpose_tile(ip, op, kx * 64, 0, HD, EE, HD, T);
  } else if (bid < 1024) {
    int r = bid - 768;
    int kx = r & 7, ny = (r >> 3) & 7, l = r >> 6;
    transpose_tile(Wo + (size_t)l * 512 * 512, WoT + (size_t)l * 512 * 512,
                   kx * 64, ny * 64, 512, 512, 512, T);
  } else if (bid < 2048) {
    int r = bid - 1024;
    int kx = r & 7, ny = (r >> 3) & 31, l = r >> 8;
    transpose_tile(fw1 + (size_t)l * 512 * 2048, W1T + (size_t)l * 2048 * 512,
                   kx * 64, ny * 64, 2048, 512, 2048, T);
  } else if (bid < 3072) {
    int r = bid - 2048;
    int kx = r & 31, ny = (r >> 5) & 7, l = r >> 8;
    transpose_tile(fw2 + (size_t)l * 2048 * 512, W2T + (size_t)l * 512 * 2048,
                   kx * 64, ny * 64, 512, 2048, 512, T);
  } else {
    int r = bid - 3072;
    int kx = r & 7, ny = r >> 3;
    transpose_tile(Wout, WoutT, kx * 64, ny * 64, VV, 512, VV, T);
  }
}

// ---------------- gemm3_64: TM=64, 3-buffer depth-3 pipeline, 1 barrier/step --
// MODE: 0=QKV scatter, 1=bias+GELU->bf16.
template<int MODE>
__global__ __launch_bounds__(256) void gemm3_64(
    const bf16_t* __restrict__ A, const bf16_t* __restrict__ Bt,
    int M, int N, int K,
    const float* __restrict__ bias, bf16_t* __restrict__ Cb,
    bf16_t* __restrict__ qo, bf16_t* __restrict__ ko, bf16_t* __restrict__ vo) {
  constexpr int TM = 64, MI = 2;
  __shared__ __align__(16) bf16_t As[3][TM * 64];
  __shared__ __align__(16) bf16_t Bs[3][128 * 64];
  int tid = threadIdx.x, lane = tid & 63, w = tid >> 6;
  int lr = lane & 15, lg = lane >> 4;
  int m0 = blockIdx.y * TM, n0 = blockIdx.x * 128;
  f32x4 acc[MI][4];
#pragma unroll
  for (int i = 0; i < MI; i++)
#pragma unroll
    for (int j = 0; j < 4; j++) acc[i][j] = (f32x4){0.f, 0.f, 0.f, 0.f};
  int wr = w >> 1, wc = w & 1;

  const bf16_t* Abase = A  + (size_t)(m0 + lr) * K + lg * 8;
  const bf16_t* Bbase = Bt + (size_t)(n0 + lr) * K + lg * 8;

  auto stage = [&](int buf, int k0) {
#pragma unroll
    for (int i = 0; i < MI; i++) {
      int c = w * MI + i;
      gload_lds16(Abase + (size_t)(c >> 1) * 16 * K + k0 + (c & 1) * 32,
                  (char*)&As[buf][0] + c * 1024);
    }
#pragma unroll
    for (int i = 0; i < 4; i++) {
      int c = w * 4 + i;
      gload_lds16(Bbase + (size_t)(c >> 1) * 16 * K + k0 + (c & 1) * 32,
                  (char*)&Bs[buf][0] + c * 1024);
    }
  };

  int nk = K >> 6;
  stage(0, 0);
  if (nk > 1) stage(1, 64);
  for (int k = 0; k < nk; k++) {
    int cur = k % 3;
    if (k + 1 < nk) asm volatile("s_waitcnt vmcnt(6)" ::: "memory");
    else            asm volatile("s_waitcnt vmcnt(0)" ::: "memory");
    __builtin_amdgcn_s_barrier();
    __builtin_amdgcn_s_setprio(1);
#pragma unroll
    for (int kk = 0; kk < 2; kk++) {
      bf16x8 afr[MI], bfr[4];
#pragma unroll
      for (int mi = 0; mi < MI; mi++)
        afr[mi] = *reinterpret_cast<const bf16x8*>(
            &As[cur][(((wr * MI + mi) << 1) + kk) * 512 + lane * 8]);
#pragma unroll
      for (int ni = 0; ni < 4; ni++)
        bfr[ni] = *reinterpret_cast<const bf16x8*>(
            &Bs[cur][(((wc * 4 + ni) << 1) + kk) * 512 + lane * 8]);
#pragma unroll
      for (int mi = 0; mi < MI; mi++)
#pragma unroll
        for (int ni = 0; ni < 4; ni++)
          acc[mi][ni] = __builtin_amdgcn_mfma_f32_16x16x32_bf16(afr[mi], bfr[ni], acc[mi][ni], 0, 0, 0);
    }
    __builtin_amdgcn_s_setprio(0);
    if (k + 2 < nk) stage((k + 2) % 3, (k + 2) << 6);
  }

#pragma unroll
  for (int mi = 0; mi < MI; mi++)
#pragma unroll
    for (int ni = 0; ni < 4; ni++) {
      int colg = n0 + wc * 64 + ni * 16 + lr;
#pragma unroll
      for (int j = 0; j < 4; j++) {
        int rowg = m0 + wr * (TM / 2) + mi * 16 + lg * 4 + j;
        float v = acc[mi][ni][j];
        if (MODE == 0) {
          int sec = colg >> 9, cc = colg & 511, hh = cc >> 6, dd = cc & 63;
          int bi = rowg >> 11, s = rowg & 2047;
          if (sec == 0)      qo[(((size_t)bi * HH + hh) * SS + s) * HD + dd] = (bf16_t)(v * 0.125f);
          else if (sec == 1) ko[(((size_t)bi * HH + hh) * SS + s) * HD + dd] = (bf16_t)v;
          else               vo[(((size_t)bi * HH + hh) * HD + dd) * SS + s] = (bf16_t)v;
        } else {
          v += bias[colg];
          v = 0.5f * v * (1.f + erff(v * 0.70710678f));
          Cb[(size_t)rowg * N + colg] = (bf16_t)v;
        }
      }
    }
}

// ---------------- layer GEMMs (Wo/FFN2): TM=32, 2-phase counted dbuf ----------
template<int MODE, int TM>
__global__ __launch_bounds__(256) void gemm_bf16(
    const bf16_t* __restrict__ A, const bf16_t* __restrict__ Bt,
    int M, int N, int K,
    const float* __restrict__ bias,
    float* __restrict__ Cf, bf16_t* __restrict__ Cb) {
  constexpr int MI = TM / 32;
  constexpr int LW = MI + 4;
  __shared__ __align__(16) bf16_t As[2][TM * 64];
  __shared__ __align__(16) bf16_t Bs[2][128 * 64];
  int tid = threadIdx.x, lane = tid & 63, w = tid >> 6;
  int lr = lane & 15, lg = lane >> 4;
  int m0 = blockIdx.y * TM, n0 = blockIdx.x * 128;
  f32x4 acc[MI][4];
#pragma unroll
  for (int i = 0; i < MI; i++)
#pragma unroll
    for (int j = 0; j < 4; j++) acc[i][j] = (f32x4){0.f, 0.f, 0.f, 0.f};
  int wr = w >> 1, wc = w & 1;

  const bf16_t* Abase = A  + (size_t)(m0 + lr) * K + lg * 8;
  const bf16_t* Bbase = Bt + (size_t)(n0 + lr) * K + lg * 8;

  auto stage = [&](int buf, int k0) {
#pragma unroll
    for (int i = 0; i < MI; i++) {
      int c = w * MI + i;
      gload_lds16(Abase + (size_t)(c >> 1) * 16 * K + k0 + (c & 1) * 32,
                  (char*)&As[buf][0] + c * 1024);
    }
#pragma unroll
    for (int i = 0; i < 4; i++) {
      int c = w * 4 + i;
      gload_lds16(Bbase + (size_t)(c >> 1) * 16 * K + k0 + (c & 1) * 32,
                  (char*)&Bs[buf][0] + c * 1024);
    }
  };

  int nk = K >> 6;
  stage(0, 0);
  for (int k = 0; k < nk; k++) {
    int cur = k & 1;
    if (k + 1 < nk) {
      stage(cur ^ 1, (k + 1) << 6);
      asm volatile("s_waitcnt vmcnt(%0)" :: "i"(LW) : "memory");
    } else {
      asm volatile("s_waitcnt vmcnt(0)" ::: "memory");
    }
    __builtin_amdgcn_s_barrier();
    __builtin_amdgcn_s_setprio(1);
#pragma unroll
    for (int kk = 0; kk < 2; kk++) {
      bf16x8 afr[MI], bfr[4];
#pragma unroll
      for (int mi = 0; mi < MI; mi++)
        afr[mi] = *reinterpret_cast<const bf16x8*>(
            &As[cur][(((wr * MI + mi) << 1) + kk) * 512 + lane * 8]);
#pragma unroll
      for (int ni = 0; ni < 4; ni++)
        bfr[ni] = *reinterpret_cast<const bf16x8*>(
            &Bs[cur][(((wc * 4 + ni) << 1) + kk) * 512 + lane * 8]);
#pragma unroll
      for (int mi = 0; mi < MI; mi++)
#pragma unroll
        for (int ni = 0; ni < 4; ni++)
          acc[mi][ni] = __builtin_amdgcn_mfma_f32_16x16x32_bf16(afr[mi], bfr[ni], acc[mi][ni], 0, 0, 0);
    }
    __builtin_amdgcn_s_setprio(0);
    __builtin_amdgcn_s_barrier();
  }

#pragma unroll
  for (int mi = 0; mi < MI; mi++)
#pragma unroll
    for (int ni = 0; ni < 4; ni++) {
      int colg = n0 + wc * 64 + ni * 16 + lr;
#pragma unroll
      for (int j = 0; j < 4; j++) {
        int rowg = m0 + wr * (TM / 2) + mi * 16 + lg * 4 + j;
        float v = acc[mi][ni][j];
        if (bias) v += bias[colg];
        Cf[(size_t)rowg * EE + colg] += v;
      }
    }
}

// ---------------- vocab GEMM: 256², single-buffer, N-fastest, NT epilogue ----
__global__ __launch_bounds__(512) void gemm256_out(
    const bf16_t* __restrict__ A, const bf16_t* __restrict__ Bt,
    const float* __restrict__ bias, float* __restrict__ C) {
  __shared__ __align__(16) char smem[64 * 260 * 4];
  bf16_t* As = (bf16_t*)smem;
  bf16_t* Bs = (bf16_t*)(smem + 32768);
  float*  Ep = (float*)smem;
  int tid = threadIdx.x, lane = tid & 63, w = tid >> 6;
  int lr = lane & 15, lg = lane >> 4;
  int bid = blockIdx.x;
  int n0 = (bid % 197) * 256, m0 = (bid / 197) * 256;   // N-fastest
  int wr = w >> 2, wc = w & 3;
  f32x4 acc[8][4];
#pragma unroll
  for (int i = 0; i < 8; i++)
#pragma unroll
    for (int j = 0; j < 4; j++) acc[i][j] = (f32x4){0.f, 0.f, 0.f, 0.f};

  const bf16_t* Abase = A  + (size_t)(m0 + lr) * 512 + lg * 8;
  const bf16_t* Bbase = Bt + (size_t)(n0 + lr) * 512 + lg * 8;

  for (int k0 = 0; k0 < 512; k0 += 64) {
#pragma unroll
    for (int i = 0; i < 4; i++) {
      int c = w * 4 + i;
      gload_lds16(Abase + (size_t)(c >> 1) * 16 * 512 + k0 + (c & 1) * 32,
                  (char*)As + c * 1024);
      gload_lds16(Bbase + (size_t)(c >> 1) * 16 * 512 + k0 + (c & 1) * 32,
                  (char*)Bs + c * 1024);
    }
    __syncthreads();
#pragma unroll
    for (int kk = 0; kk < 2; kk++) {
      bf16x8 afr[8], bfr[4];
#pragma unroll
      for (int mi = 0; mi < 8; mi++)
        afr[mi] = *reinterpret_cast<const bf16x8*>(
            &As[(((wr * 8 + mi) << 1) + kk) * 512 + lane * 8]);
#pragma unroll
      for (int ni = 0; ni < 4; ni++)
        bfr[ni] = *reinterpret_cast<const bf16x8*>(
            &Bs[(((wc * 4 + ni) << 1) + kk) * 512 + lane * 8]);
#pragma unroll
      for (int mi = 0; mi < 8; mi++)
#pragma unroll
        for (int ni = 0; ni < 4; ni++)
          acc[mi][ni] = __builtin_amdgcn_mfma_f32_16x16x32_bf16(afr[mi], bfr[ni], acc[mi][ni], 0, 0, 0);
    }
    __syncthreads();
  }

  int colBase = n0 + (tid & 63) * 4;
  float b0 = 0.f, b1 = 0.f, b2 = 0.f, b3 = 0.f;
  if (colBase + 3 < VV) {
    float4 bv = *reinterpret_cast<const float4*>(bias + colBase);
    b0 = bv.x; b1 = bv.y; b2 = bv.z; b3 = bv.w;
  } else {
    if (colBase     < VV) b0 = bias[colBase];
    if (colBase + 1 < VV) b1 = bias[colBase + 1];
    if (colBase + 2 < VV) b2 = bias[colBase + 2];
  }
  int rw = tid >> 6;
  for (int ch = 0; ch < 4; ch++) {
    __syncthreads();
    if (wr == (ch >> 1)) {
      int mib = (ch & 1) * 4;
#pragma unroll
      for (int mi2 = 0; mi2 < 4; mi2++)
#pragma unroll
        for (int ni = 0; ni < 4; ni++) {
          int col = wc * 64 + ni * 16 + lr;
#pragma unroll
          for (int j = 0; j < 4; j++)
            Ep[(mi2 * 16 + lg * 4 + j) * 260 + col] = acc[mib + mi2][ni][j];
        }
    }
    __syncthreads();
#pragma unroll
    for (int pass = 0; pass < 8; pass++) {
      int r = pass * 8 + rw;
      f32x4 v = *reinterpret_cast<const f32x4*>(&Ep[r * 260 + (tid & 63) * 4]);
      v[0] += b0; v[1] += b1; v[2] += b2; v[3] += b3;
      float* dst = &C[(size_t)(m0 + ch * 64 + r) * VV + colBase];
      if (colBase + 3 < VV) {
        __builtin_nontemporal_store(v, reinterpret_cast<f32x4*>(dst));
      } else {
        if (colBase     < VV) __builtin_nontemporal_store(v[0], dst);
        if (colBase + 1 < VV) __builtin_nontemporal_store(v[1], dst + 1);
        if (colBase + 2 < VV) __builtin_nontemporal_store(v[2], dst + 2);
      }
    }
  }
}

// ---------------- flash attention v5: QBLK=64, 3-buffer depth-3 K/V pipeline --
#define QBLK 64
#define KVB 64
__global__ __launch_bounds__(256) void attn_kernel(
    const bf16_t* __restrict__ qb, const bf16_t* __restrict__ kb,
    const bf16_t* __restrict__ vT, const int* __restrict__ amask,
    bf16_t* __restrict__ ab) {
  __shared__ bf16_t Qs[QBLK][72];
  __shared__ bf16_t Ps[QBLK][72];
  __shared__ __align__(16) bf16_t Ks[3][KVB * 64];
  __shared__ __align__(16) bf16_t Vs[3][KVB * 64];
  __shared__ float kmAll[SS];
  int tid = threadIdx.x, lane = tid & 63, w = tid >> 6;
  int lr = lane & 15, lg = lane >> 4;
  int bid = blockIdx.x;
  int bh = bid & 15;
  int qi = bid >> 4;
  int qq = (qi < 16) ? qi : 47 - qi;
  int q0 = qq * QBLK;
  int b = bh >> 3, h = bh & 7;
  const bf16_t* Qg = qb + (size_t)bh * SS * HD;
  const bf16_t* Kg = kb + (size_t)bh * SS * HD;
  const bf16_t* Vg = vT + (size_t)bh * HD * SS;

  {
    int r = tid >> 2, c = (tid & 3) * 16;
    const uint4* s = reinterpret_cast<const uint4*>(Qg + (size_t)(q0 + r) * HD + c);
    uint4 a0 = s[0], a1 = s[1];
    *reinterpret_cast<uint4*>(&Qs[r][c])     = a0;
    *reinterpret_cast<uint4*>(&Qs[r][c + 8]) = a1;
  }
#pragma unroll
  for (int i = 0; i < 8; i++) {
    int s = i * 256 + tid;
    kmAll[s] = amask[b * SS + s] ? 0.f : -1e30f;
  }

  auto stageKV = [&](int buf, int kv0) {
#pragma unroll
    for (int i = 0; i < 4; i++) {
      int c = w * 4 + i;
      if (c < 8) {
        gload_lds16(Kg + (size_t)(kv0 + (c >> 1) * 16 + lr) * HD + (c & 1) * 32 + lg * 8,
                    (char*)&Ks[buf][0] + c * 1024);
      } else {
        int cc = c - 8;
        gload_lds16(Vg + (size_t)((cc >> 1) * 16 + lr) * SS + kv0 + (cc & 1) * 32 + lg * 8,
                    (char*)&Vs[buf][0] + cc * 1024);
      }
    }
  };

  f32x4 o[4];
  f32x4 m_run, l_run;
  m_run = (f32x4){-1e30f, -1e30f, -1e30f, -1e30f};
  l_run = (f32x4){0.f, 0.f, 0.f, 0.f};
#pragma unroll
  for (int nd = 0; nd < 4; nd++) o[nd] = (f32x4){0.f, 0.f, 0.f, 0.f};

  int ntile = qq + 1;
  stageKV(0, 0);
  if (ntile > 1) stageKV(1, KVB);
  __syncthreads();

  for (int t = 0; t < ntile; t++) {
    int buf = t % 3;
    int kv0 = t * KVB;
    if (t + 1 < ntile) asm volatile("s_waitcnt vmcnt(4)" ::: "memory");
    else               asm volatile("s_waitcnt vmcnt(0)" ::: "memory");
    __builtin_amdgcn_s_barrier();

    f32x4 sc[4];
#pragma unroll
    for (int ni = 0; ni < 4; ni++) sc[ni] = (f32x4){0.f, 0.f, 0.f, 0.f};
#pragma unroll
    for (int kk = 0; kk < 2; kk++) {
      bf16x8 af = *reinterpret_cast<const bf16x8*>(&Qs[w * 16 + lr][kk * 32 + lg * 8]);
      bf16x8 bf[4];
#pragma unroll
      for (int ni = 0; ni < 4; ni++)
        bf[ni] = *reinterpret_cast<const bf16x8*>(&Ks[buf][((ni << 1) + kk) * 512 + lane * 8]);
#pragma unroll
      for (int ni = 0; ni < 4; ni++)
        sc[ni] = __builtin_amdgcn_mfma_f32_16x16x32_bf16(af, bf[ni], sc[ni], 0, 0, 0);
    }

    {
      int qrb = q0 + w * 16 + lg * 4;
      float kmv[4];
#pragma unroll
      for (int ni = 0; ni < 4; ni++) kmv[ni] = kmAll[kv0 + ni * 16 + lr];
#pragma unroll
      for (int ni = 0; ni < 4; ni++) {
        int kg = kv0 + ni * 16 + lr;
#pragma unroll
        for (int j = 0; j < 4; j++) {
          float s = sc[ni][j] + kmv[ni];
          sc[ni][j] = (kg <= qrb + j) ? s : -1e30f;
        }
      }
      f32x4 rmax = sc[0];
#pragma unroll
      for (int ni = 1; ni < 4; ni++)
#pragma unroll
        for (int j = 0; j < 4; j++) rmax[j] = fmaxf(rmax[j], sc[ni][j]);
#pragma unroll
      for (int msk = 1; msk <= 8; msk <<= 1)
#pragma unroll
        for (int j = 0; j < 4; j++) rmax[j] = fmaxf(rmax[j], __shfl_xor(rmax[j], msk));
      f32x4 mnew, corr;
#pragma unroll
      for (int j = 0; j < 4; j++) {
        mnew[j] = fmaxf(m_run[j], rmax[j]);
        corr[j] = __expf(m_run[j] - mnew[j]);
      }
      m_run = mnew;
      f32x4 rs = (f32x4){0.f, 0.f, 0.f, 0.f};
#pragma unroll
      for (int ni = 0; ni < 4; ni++) {
#pragma unroll
        for (int j = 0; j < 4; j++) {
          float p = __expf(sc[ni][j] - mnew[j]);
          rs[j] += p;
          Ps[w * 16 + lg * 4 + j][ni * 16 + lr] = (bf16_t)p;
        }
      }
#pragma unroll
      for (int msk = 1; msk <= 8; msk <<= 1)
#pragma unroll
        for (int j = 0; j < 4; j++) rs[j] += __shfl_xor(rs[j], msk);
#pragma unroll
      for (int j = 0; j < 4; j++) l_run[j] = l_run[j] * corr[j] + rs[j];
#pragma unroll
      for (int nd = 0; nd < 4; nd++) o[nd] = o[nd] * corr;
    }

#pragma unroll
    for (int kc = 0; kc < 2; kc++) {
      bf16x8 pa = *reinterpret_cast<const bf16x8*>(&Ps[w * 16 + lr][kc * 32 + lg * 8]);
      bf16x8 vb[4];
#pragma unroll
      for (int nd = 0; nd < 4; nd++)
        vb[nd] = *reinterpret_cast<const bf16x8*>(&Vs[buf][((nd << 1) + kc) * 512 + lane * 8]);
#pragma unroll
      for (int nd = 0; nd < 4; nd++)
        o[nd] = __builtin_amdgcn_mfma_f32_16x16x32_bf16(pa, vb[nd], o[nd], 0, 0, 0);
    }

    if (t + 2 < ntile) stageKV((t + 2) % 3, kv0 + 2 * KVB);
  }

  f32x4 linv;
#pragma unroll
  for (int j = 0; j < 4; j++) linv[j] = 1.f / l_run[j];
#pragma unroll
  for (int nd = 0; nd < 4; nd++)
#pragma unroll
    for (int j = 0; j < 4; j++) {
      int rowg = b * SS + q0 + w * 16 + lg * 4 + j;
      int col = h * HD + nd * 16 + lr;
      ab[(size_t)rowg * EE + col] = (bf16_t)(o[nd][j] * linv[j]);
    }
}

extern "C" void kernel_launch(void* const* d_in, const int* in_sizes, int n_in,
                              void* d_out, int out_size, void* d_ws, size_t ws_size,
                              hipStream_t stream) {
  const int*   ids   = (const int*)d_in[0];
  const int*   amask = (const int*)d_in[1];
  const float* emb   = (const float*)d_in[2];
  const float* Wq    = (const float*)d_in[3];
  const float* Wk    = (const float*)d_in[4];
  const float* Wv    = (const float*)d_in[5];
  const float* Wo    = (const float*)d_in[6];
  const float* ln1g  = (const float*)d_in[7];
  const float* ln1b  = (const float*)d_in[8];
  const float* ln2g  = (const float*)d_in[9];
  const float* ln2b  = (const float*)d_in[10];
  const float* fw1   = (const float*)d_in[11];
  const float* fb1   = (const float*)d_in[12];
  const float* fw2   = (const float*)d_in[13];
  const float* fb2   = (const float*)d_in[14];
  const float* lnfg  = (const float*)d_in[15];
  const float* lnfb  = (const float*)d_in[16];
  const float* Wout  = (const float*)d_in[17];
  const float* bout  = (const float*)d_in[18];
  float* out = (float*)d_out;

  float*  x     = (float*)d_ws;
  bf16_t* xn    = (bf16_t*)((char*)d_ws + (8u << 20));
  bf16_t* WoutT = (bf16_t*)((char*)d_ws + (12u << 20));
  char* sc = (char*)d_out;
  bf16_t* qbuf = (bf16_t*)(sc);
  bf16_t* kbuf = (bf16_t*)(sc + 4194304);
  bf16_t* vTb  = (bf16_t*)(sc + 8388608);
  bf16_t* ab   = (bf16_t*)(sc + 12582912);
  bf16_t* hb   = (bf16_t*)(sc + 16777216);
  bf16_t* Wqkv = (bf16_t*)(sc + 33554432);
  bf16_t* WoT  = (bf16_t*)(sc + 39845888);
  bf16_t* W1T  = (bf16_t*)(sc + 41943040);
  bf16_t* W2T  = (bf16_t*)(sc + 50331648);

  wconv_all<<<dim3(3072 + 8 * (VPAD2 / 64)), 256, 0, stream>>>(
      Wq, Wk, Wv, Wo, fw1, fw2, Wout, Wqkv, WoT, W1T, W2T, WoutT);

  embed_ln_kernel<<<NTOK / 4, 256, 0, stream>>>(ids, emb, ln1g, ln1b, x, xn);

  for (int l = 0; l < LL; l++) {
    if (l > 0)
      ln_kernel<<<NTOK / 4, 256, 0, stream>>>(x, xn, ln1g + l * EE, ln1b + l * EE);
    gemm3_64<0><<<dim3(12, 64), 256, 0, stream>>>(xn, Wqkv + (size_t)l * 1536 * 512,
        NTOK, 1536, 512, nullptr, nullptr, qbuf, kbuf, vTb);
    attn_kernel<<<dim3(512), 256, 0, stream>>>(qbuf, kbuf, vTb, amask, ab);
    gemm_bf16<2, 32><<<dim3(4, 128), 256, 0, stream>>>(ab, WoT + (size_t)l * 512 * 512,
        NTOK, 512, 512, nullptr, x, nullptr);
    ln_kernel<<<NTOK / 4, 256, 0, stream>>>(x, xn, ln2g + l * EE, ln2b + l * EE);
    gemm3_64<1><<<dim3(16, 64), 256, 0, stream>>>(xn, W1T + (size_t)l * 2048 * 512,
        NTOK, 2048, 512, fb1 + l * 2048, hb, nullptr, nullptr, nullptr);
    gemm_bf16<2, 32><<<dim3(4, 128), 256, 0, stream>>>(hb, W2T + (size_t)l * 512 * 2048,
        NTOK, 512, 2048, fb2 + l * EE, x, nullptr);
  }
  ln_kernel<<<NTOK / 4, 256, 0, stream>>>(x, xn, lnfg, lnfb);
  gemm256_out<<<dim3(16 * (VPAD2 / 256)), 512, 0, stream>>>(xn, WoutT, bout, out);
}